// Round 10
// baseline (74.896 us; speedup 1.0000x reference)
//
#include <hip/hip_runtime.h>
#include <hip/hip_fp16.h>

// Local attention block: 40^3 volume, C=64, 4 heads of hd=16, 3x3x3 window,
// replicate padding, residual add. f32 in/out.
//
// All intermediates in FP16 (more mantissa than bf16; range safe here).
// Kernel 1: proj via MFMA 16x16x32 f16, W-pack folded in. Q,K,V -> f16
//           [N][64], Q pre-scaled 1/4.
// Kernel 2: attention, block = (4x8x8 tile, ONE head), K/V halo in LDS
//           (16B-lane-stride layout, measured conflict-free). Packed-f16
//           math (v_pk_fma_f16): QK = 8 hfma2, PV = 8 hfma2 per neighbor.
//           T14 split: K->LDS, raw s_barrier (lgkmcnt only) keeps V global
//           loads in flight; V->LDS written after QK pass.

#define NVOX 64000   // 40*40*40
#define DIM 40
#define CCH 64
#define HEADS 4
#define HD 16

// attn tile geometry (one head per block)
#define ATZ 4
#define ATY 8
#define ATX 8
#define ANH 600           // 6*10*10 halo voxels

typedef __attribute__((ext_vector_type(8))) _Float16 f16x8;
typedef __attribute__((ext_vector_type(4))) float f32x4;

__device__ __forceinline__ unsigned pkh(float a, float b) {
    __half2 h = __floats2half2_rn(a, b);
    return *reinterpret_cast<unsigned*>(&h);
}
__device__ __forceinline__ __half2 u2h(unsigned u) {
    __half2 h; *reinterpret_cast<unsigned*>(&h) = u; return h;
}

__device__ __forceinline__ int xcd_swz(int b) {   // bijective, 1000 % 8 == 0
    return (b & 7) * 125 + (b >> 3);
}

__global__ __launch_bounds__(256) void proj_mfma(
    const float* __restrict__ x,
    const float* __restrict__ Wq, const float* __restrict__ bq,
    const float* __restrict__ Wk, const float* __restrict__ bk,
    const float* __restrict__ Wv, const float* __restrict__ bv,
    unsigned short* __restrict__ Qg, unsigned short* __restrict__ Kg,
    unsigned short* __restrict__ Vg)
{
    // All LDS tiles 16B-granular: [chunk][row/vox][8 ch] -> 16 B lane stride.
    __shared__ __align__(16) unsigned short Wl[8 * 192 * 8];  // 24576 B
    __shared__ __align__(16) unsigned short xl[8 * 64 * 8];   //  8192 B
    __shared__ __align__(16) float bl[192];                   //   768 B

    const int tid = threadIdx.x;
    const int bid = xcd_swz((int)blockIdx.x);
    const int n0 = bid * 64;

    // ---- Stage W + bias: thread t<192 owns one output row ----
    if (tid < 192) {
        const float* Wsrc; const float* bsrc; float sc; int r;
        if (tid < 64)       { Wsrc = Wq; bsrc = bq; sc = 0.25f; r = tid; }
        else if (tid < 128) { Wsrc = Wk; bsrc = bk; sc = 1.0f;  r = tid - 64; }
        else                { Wsrc = Wv; bsrc = bv; sc = 1.0f;  r = tid - 128; }
        const float4* wr = reinterpret_cast<const float4*>(Wsrc + r * 64);
        #pragma unroll
        for (int c = 0; c < 8; ++c) {            // chunk = 8 ch = 2 float4
            const float4 f0 = wr[2 * c], f1 = wr[2 * c + 1];
            *reinterpret_cast<uint4*>(&Wl[(c * 192 + tid) * 8]) =
                make_uint4(pkh(sc * f0.x, sc * f0.y), pkh(sc * f0.z, sc * f0.w),
                           pkh(sc * f1.x, sc * f1.y), pkh(sc * f1.z, sc * f1.w));
        }
        bl[tid] = sc * bsrc[r];
    }
    // ---- Stage x tile: 512 items = (chunk, vox) ----
    #pragma unroll
    for (int i = 0; i < 2; ++i) {
        const int item = tid + i * 256;
        const int v = item & 63, c = item >> 6;      // c: 0..3 then 4..7
        float f[8];
        #pragma unroll
        for (int j = 0; j < 8; ++j)
            f[j] = x[(c * 8 + j) * NVOX + n0 + v];   // coalesced across lanes
        *reinterpret_cast<uint4*>(&xl[(c * 64 + v) * 8]) =
            make_uint4(pkh(f[0], f[1]), pkh(f[2], f[3]),
                       pkh(f[4], f[5]), pkh(f[6], f[7]));
    }
    __syncthreads();

    const int lane = tid & 63;
    const int wv   = tid >> 6;
    const int l15  = lane & 15;
    const int l4   = lane >> 4;
    const int vox  = wv * 16 + l15;
    const int n    = n0 + vox;               // D col = lane&15 -> voxel

    const f16x8 bx0 = *reinterpret_cast<const f16x8*>(&xl[(l4 * 64 + vox) * 8]);
    const f16x8 bx1 = *reinterpret_cast<const f16x8*>(&xl[((l4 + 4) * 64 + vox) * 8]);

    #pragma unroll
    for (int rb = 0; rb < 12; ++rb) {
        const int row = rb * 16 + l15;       // A row, k-chunks l4 / l4+4
        const f16x8 a0 = *reinterpret_cast<const f16x8*>(&Wl[(l4 * 192 + row) * 8]);
        const f16x8 a1 = *reinterpret_cast<const f16x8*>(&Wl[((l4 + 4) * 192 + row) * 8]);

        f32x4 acc = {0.f, 0.f, 0.f, 0.f};
        acc = __builtin_amdgcn_mfma_f32_16x16x32_f16(a0, bx0, acc, 0, 0, 0);
        acc = __builtin_amdgcn_mfma_f32_16x16x32_f16(a1, bx1, acc, 0, 0, 0);

        const int r0 = rb * 16 + l4 * 4;     // D rows r0..r0+3 for this lane
        const float4 bs = *reinterpret_cast<const float4*>(&bl[r0]);
        const int rr = r0 & 63;              // row within its matrix
        unsigned short* og = (rb < 4) ? Qg : (rb < 8) ? Kg : Vg;
        *reinterpret_cast<uint2*>(&og[(size_t)n * CCH + rr]) =
            make_uint2(pkh(acc[0] + bs.x, acc[1] + bs.y),
                       pkh(acc[2] + bs.z, acc[3] + bs.w));
    }
}

__global__ __launch_bounds__(256, 4) void attn_kernel(
    const float* __restrict__ x,
    const unsigned short* __restrict__ Qg, const unsigned short* __restrict__ Kg,
    const unsigned short* __restrict__ Vg,
    float* __restrict__ out)
{
    // LDS per matrix: [half(8ch)][600 halo voxels][8 f16] -> 16 B lane stride
    __shared__ __align__(16) unsigned short Kl[2 * ANH * 8];   // 19200 B
    __shared__ __align__(16) unsigned short Vl[2 * ANH * 8];   // 19200 B

    const int tid = threadIdx.x;
    const int bid = xcd_swz((int)blockIdx.x);   // 250 tiles x 4 heads
    const int h    = bid & 3;
    const int tile = bid >> 2;
    const int tx = tile % 5;
    const int ty = (tile / 5) % 5;
    const int tz = tile / 25;
    const int z0 = tz * ATZ - 1, y0 = ty * ATY - 1, x0 = tx * ATX - 1;

    // ---- Own voxel; issue Q load first (oldest -> stays cheap to wait on) ----
    const int vox = tid;                   // 256 voxels, one head
    const int lz = vox >> 6, ly = (vox >> 3) & 7, lx = vox & 7;
    const int gz = tz * ATZ + lz, gy = ty * ATY + ly, gx = tx * ATX + lx;
    const int n = (gz * DIM + gy) * DIM + gx;

    const uint4 q01 = *reinterpret_cast<const uint4*>(&Qg[(size_t)n * CCH + h * HD]);
    const uint4 q23 = *reinterpret_cast<const uint4*>(&Qg[(size_t)n * CCH + h * HD + 8]);

    // ---- Stage K to LDS; V only to regs (T14: stays in flight past barrier) ----
    uint4 vs0[3], vs1[3];
    #pragma unroll
    for (int i = 0; i < 3; ++i) {
        const int ml = tid + i * 256;
        if (ml < ANH) {
            const int hz = ml / 100; const int r = ml - hz * 100;
            const int hy = r / 10;   const int hx = r - hy * 10;
            const int sz = min(max(z0 + hz, 0), DIM - 1);
            const int sy = min(max(y0 + hy, 0), DIM - 1);
            const int sx = min(max(x0 + hx, 0), DIM - 1);
            const size_t base = (size_t)((sz * DIM + sy) * DIM + sx) * CCH + h * HD;
            const uint4 k0 = *reinterpret_cast<const uint4*>(&Kg[base]);
            const uint4 k1 = *reinterpret_cast<const uint4*>(&Kg[base + 8]);
            vs0[i] = *reinterpret_cast<const uint4*>(&Vg[base]);
            vs1[i] = *reinterpret_cast<const uint4*>(&Vg[base + 8]);
            *reinterpret_cast<uint4*>(&Kl[ml * 8])           = k0;
            *reinterpret_cast<uint4*>(&Kl[ANH * 8 + ml * 8]) = k1;
        }
    }
    // Raw barrier: drain only LDS writes; V global loads remain outstanding.
    asm volatile("s_waitcnt lgkmcnt(0)" ::: "memory");
    __builtin_amdgcn_s_barrier();
    __builtin_amdgcn_sched_barrier(0);

    __half2 qh[8];
    qh[0] = u2h(q01.x); qh[1] = u2h(q01.y); qh[2] = u2h(q01.z); qh[3] = u2h(q01.w);
    qh[4] = u2h(q23.x); qh[5] = u2h(q23.y); qh[6] = u2h(q23.z); qh[7] = u2h(q23.w);

    const int mlc = (lz + 1) * 100 + (ly + 1) * 10 + (lx + 1);
    const uint4* kb = reinterpret_cast<const uint4*>(Kl) + mlc;
    const uint4* vb = reinterpret_cast<const uint4*>(Vl) + mlc;

    // ---- QK pass: 27 logits, packed-f16 dot products ----
    float p[27];                 // statically indexed (fully unrolled)
    float s = 0.0f;
    #pragma unroll
    for (int dz = -1; dz <= 1; ++dz) {
        #pragma unroll
        for (int dy = -1; dy <= 1; ++dy) {
            #pragma unroll
            for (int dx = -1; dx <= 1; ++dx) {
                const int off = dz * 100 + dy * 10 + dx;
                const uint4 ka = kb[off];          // ch 0-7  (4x f16x2)
                const uint4 kc = kb[off + ANH];    // ch 8-15
                __half2 acc2 = __hmul2(qh[0], u2h(ka.x));
                acc2 = __hfma2(qh[1], u2h(ka.y), acc2);
                acc2 = __hfma2(qh[2], u2h(ka.z), acc2);
                acc2 = __hfma2(qh[3], u2h(ka.w), acc2);
                acc2 = __hfma2(qh[4], u2h(kc.x), acc2);
                acc2 = __hfma2(qh[5], u2h(kc.y), acc2);
                acc2 = __hfma2(qh[6], u2h(kc.z), acc2);
                acc2 = __hfma2(qh[7], u2h(kc.w), acc2);
                const float lg = __low2float(acc2) + __high2float(acc2);
                // max-free softmax: logits ~N(0,1); e^|lg| far from f16/f32 limits
                const float e = __expf(lg);
                const int w = (dz + 1) * 9 + (dy + 1) * 3 + (dx + 1);
                p[w] = e;
                s += e;
            }
        }
    }

    // ---- Dump V regs to LDS (compiler waits vmcnt for the V data) ----
    #pragma unroll
    for (int i = 0; i < 3; ++i) {
        const int ml = tid + i * 256;
        if (ml < ANH) {
            *reinterpret_cast<uint4*>(&Vl[ml * 8])           = vs0[i];
            *reinterpret_cast<uint4*>(&Vl[ANH * 8 + ml * 8]) = vs1[i];
        }
    }
    __syncthreads();

    // ---- PV pass: packed-f16 accumulate ----
    __half2 av[8];
    #pragma unroll
    for (int i = 0; i < 8; ++i) av[i] = __float2half2_rn(0.0f);

    #pragma unroll
    for (int dz = -1; dz <= 1; ++dz) {
        #pragma unroll
        for (int dy = -1; dy <= 1; ++dy) {
            #pragma unroll
            for (int dx = -1; dx <= 1; ++dx) {
                const int off = dz * 100 + dy * 10 + dx;
                const int w = (dz + 1) * 9 + (dy + 1) * 3 + (dx + 1);
                const __half2 e2 = __float2half2_rn(p[w]);
                const uint4 va = vb[off];
                const uint4 vc = vb[off + ANH];
                av[0] = __hfma2(e2, u2h(va.x), av[0]);
                av[1] = __hfma2(e2, u2h(va.y), av[1]);
                av[2] = __hfma2(e2, u2h(va.z), av[2]);
                av[3] = __hfma2(e2, u2h(va.w), av[3]);
                av[4] = __hfma2(e2, u2h(vc.x), av[4]);
                av[5] = __hfma2(e2, u2h(vc.y), av[5]);
                av[6] = __hfma2(e2, u2h(vc.z), av[6]);
                av[7] = __hfma2(e2, u2h(vc.w), av[7]);
            }
        }
    }

    const float rs = 1.0f / s;
    const int cb = h * HD;
    #pragma unroll
    for (int i = 0; i < 8; ++i) {
        const size_t i0 = (size_t)(cb + 2 * i) * NVOX + n;
        const size_t i1 = (size_t)(cb + 2 * i + 1) * NVOX + n;
        out[i0] = x[i0] + __low2float(av[i]) * rs;    // coalesced across lanes
        out[i1] = x[i1] + __high2float(av[i]) * rs;
    }
}

extern "C" void kernel_launch(void* const* d_in, const int* in_sizes, int n_in,
                              void* d_out, int out_size, void* d_ws, size_t ws_size,
                              hipStream_t stream) {
    const float* x  = (const float*)d_in[0];
    // d_in[1] = cemb (unused by the reference)
    const float* Wq = (const float*)d_in[2];
    const float* bq = (const float*)d_in[3];
    const float* Wk = (const float*)d_in[4];
    const float* bk = (const float*)d_in[5];
    const float* Wv = (const float*)d_in[6];
    const float* bv = (const float*)d_in[7];
    float* out = (float*)d_out;

    unsigned short* Qg = (unsigned short*)d_ws;        // f16 [N][64]
    unsigned short* Kg = Qg + (size_t)NVOX * CCH;      // f16 [N][64]
    unsigned short* Vg = Kg + (size_t)NVOX * CCH;      // f16 [N][64]

    proj_mfma<<<dim3(1000), dim3(256), 0, stream>>>(
        x, Wq, bq, Wk, bk, Wv, bv, Qg, Kg, Vg);
    attn_kernel<<<dim3(1000), dim3(256), 0, stream>>>(
        x, Qg, Kg, Vg, out);
}

// Round 11
// 38.118 us; speedup vs baseline: 1.9648x; 1.9648x over previous
//
#include <hip/hip_runtime.h>
#include <hip/hip_fp16.h>

// Local attention block: 40^3 volume, C=64, 4 heads of hd=16, 3x3x3 window,
// replicate padding, residual add. f32 in/out.
//
// All intermediates FP16. Kernel 1: proj via MFMA 16x16x32 f16, W-pack
// folded in; Q,K,V -> f16 [N][64], Q pre-scaled 1/4. Kernel 2: attention,
// block = (4x8x8 tile, ONE head), K+V halo staged to LDS up front, ONE
// fused QK+PV pass (round-9 structure: minimal live registers, no spills),
// packed-f16 hfma2 math. PV accumulated with e/16 for f16 range headroom.

#define NVOX 64000   // 40*40*40
#define DIM 40
#define CCH 64
#define HEADS 4
#define HD 16

// attn tile geometry (one head per block)
#define ATZ 4
#define ATY 8
#define ATX 8
#define ANH 600           // 6*10*10 halo voxels

typedef __attribute__((ext_vector_type(8))) _Float16 f16x8;
typedef __attribute__((ext_vector_type(4))) float f32x4;

__device__ __forceinline__ unsigned pkh(float a, float b) {
    __half2 h = __floats2half2_rn(a, b);
    return *reinterpret_cast<unsigned*>(&h);
}
__device__ __forceinline__ __half2 u2h(unsigned u) {
    __half2 h; *reinterpret_cast<unsigned*>(&h) = u; return h;
}

__device__ __forceinline__ int xcd_swz(int b) {   // bijective, 1000 % 8 == 0
    return (b & 7) * 125 + (b >> 3);
}

__global__ __launch_bounds__(256) void proj_mfma(
    const float* __restrict__ x,
    const float* __restrict__ Wq, const float* __restrict__ bq,
    const float* __restrict__ Wk, const float* __restrict__ bk,
    const float* __restrict__ Wv, const float* __restrict__ bv,
    unsigned short* __restrict__ Qg, unsigned short* __restrict__ Kg,
    unsigned short* __restrict__ Vg)
{
    // All LDS tiles 16B-granular: [chunk][row/vox][8 ch] -> 16 B lane stride.
    __shared__ __align__(16) unsigned short Wl[8 * 192 * 8];  // 24576 B
    __shared__ __align__(16) unsigned short xl[8 * 64 * 8];   //  8192 B
    __shared__ __align__(16) float bl[192];                   //   768 B

    const int tid = threadIdx.x;
    const int bid = xcd_swz((int)blockIdx.x);
    const int n0 = bid * 64;

    // ---- Stage W + bias: thread t<192 owns one output row ----
    if (tid < 192) {
        const float* Wsrc; const float* bsrc; float sc; int r;
        if (tid < 64)       { Wsrc = Wq; bsrc = bq; sc = 0.25f; r = tid; }
        else if (tid < 128) { Wsrc = Wk; bsrc = bk; sc = 1.0f;  r = tid - 64; }
        else                { Wsrc = Wv; bsrc = bv; sc = 1.0f;  r = tid - 128; }
        const float4* wr = reinterpret_cast<const float4*>(Wsrc + r * 64);
        #pragma unroll
        for (int c = 0; c < 8; ++c) {            // chunk = 8 ch = 2 float4
            const float4 f0 = wr[2 * c], f1 = wr[2 * c + 1];
            *reinterpret_cast<uint4*>(&Wl[(c * 192 + tid) * 8]) =
                make_uint4(pkh(sc * f0.x, sc * f0.y), pkh(sc * f0.z, sc * f0.w),
                           pkh(sc * f1.x, sc * f1.y), pkh(sc * f1.z, sc * f1.w));
        }
        bl[tid] = sc * bsrc[r];
    }
    // ---- Stage x tile: 512 items = (chunk, vox) ----
    #pragma unroll
    for (int i = 0; i < 2; ++i) {
        const int item = tid + i * 256;
        const int v = item & 63, c = item >> 6;      // c: 0..3 then 4..7
        float f[8];
        #pragma unroll
        for (int j = 0; j < 8; ++j)
            f[j] = x[(c * 8 + j) * NVOX + n0 + v];   // coalesced across lanes
        *reinterpret_cast<uint4*>(&xl[(c * 64 + v) * 8]) =
            make_uint4(pkh(f[0], f[1]), pkh(f[2], f[3]),
                       pkh(f[4], f[5]), pkh(f[6], f[7]));
    }
    __syncthreads();

    const int lane = tid & 63;
    const int wv   = tid >> 6;
    const int l15  = lane & 15;
    const int l4   = lane >> 4;
    const int vox  = wv * 16 + l15;
    const int n    = n0 + vox;               // D col = lane&15 -> voxel

    const f16x8 bx0 = *reinterpret_cast<const f16x8*>(&xl[(l4 * 64 + vox) * 8]);
    const f16x8 bx1 = *reinterpret_cast<const f16x8*>(&xl[((l4 + 4) * 64 + vox) * 8]);

    #pragma unroll
    for (int rb = 0; rb < 12; ++rb) {
        const int row = rb * 16 + l15;       // A row, k-chunks l4 / l4+4
        const f16x8 a0 = *reinterpret_cast<const f16x8*>(&Wl[(l4 * 192 + row) * 8]);
        const f16x8 a1 = *reinterpret_cast<const f16x8*>(&Wl[((l4 + 4) * 192 + row) * 8]);

        f32x4 acc = {0.f, 0.f, 0.f, 0.f};
        acc = __builtin_amdgcn_mfma_f32_16x16x32_f16(a0, bx0, acc, 0, 0, 0);
        acc = __builtin_amdgcn_mfma_f32_16x16x32_f16(a1, bx1, acc, 0, 0, 0);

        const int r0 = rb * 16 + l4 * 4;     // D rows r0..r0+3 for this lane
        const float4 bs = *reinterpret_cast<const float4*>(&bl[r0]);
        const int rr = r0 & 63;              // row within its matrix
        unsigned short* og = (rb < 4) ? Qg : (rb < 8) ? Kg : Vg;
        *reinterpret_cast<uint2*>(&og[(size_t)n * CCH + rr]) =
            make_uint2(pkh(acc[0] + bs.x, acc[1] + bs.y),
                       pkh(acc[2] + bs.z, acc[3] + bs.w));
    }
}

__global__ __launch_bounds__(256, 4) void attn_kernel(
    const float* __restrict__ x,
    const unsigned short* __restrict__ Qg, const unsigned short* __restrict__ Kg,
    const unsigned short* __restrict__ Vg,
    float* __restrict__ out)
{
    // LDS per matrix: [half(8ch)][600 halo voxels][8 f16] -> 16 B lane stride
    __shared__ __align__(16) unsigned short Kl[2 * ANH * 8];   // 19200 B
    __shared__ __align__(16) unsigned short Vl[2 * ANH * 8];   // 19200 B

    const int tid = threadIdx.x;
    const int bid = xcd_swz((int)blockIdx.x);   // 250 tiles x 4 heads
    const int h    = bid & 3;
    const int tile = bid >> 2;
    const int tx = tile % 5;
    const int ty = (tile / 5) % 5;
    const int tz = tile / 25;
    const int z0 = tz * ATZ - 1, y0 = ty * ATY - 1, x0 = tx * ATX - 1;

    // ---- Own voxel; issue Q load first so it hides under staging ----
    const int vox = tid;                   // 256 voxels, one head
    const int lz = vox >> 6, ly = (vox >> 3) & 7, lx = vox & 7;
    const int gz = tz * ATZ + lz, gy = ty * ATY + ly, gx = tx * ATX + lx;
    const int n = (gz * DIM + gy) * DIM + gx;

    const uint4 q01 = *reinterpret_cast<const uint4*>(&Qg[(size_t)n * CCH + h * HD]);
    const uint4 q23 = *reinterpret_cast<const uint4*>(&Qg[(size_t)n * CCH + h * HD + 8]);

    // ---- Stage K+V halo: 600 items, 32 B of K + 32 B of V each ----
    #pragma unroll
    for (int i = 0; i < 3; ++i) {
        const int ml = tid + i * 256;
        if (ml < ANH) {
            const int hz = ml / 100; const int r = ml - hz * 100;
            const int hy = r / 10;   const int hx = r - hy * 10;
            const int sz = min(max(z0 + hz, 0), DIM - 1);
            const int sy = min(max(y0 + hy, 0), DIM - 1);
            const int sx = min(max(x0 + hx, 0), DIM - 1);
            const size_t base = (size_t)((sz * DIM + sy) * DIM + sx) * CCH + h * HD;
            const uint4 k0 = *reinterpret_cast<const uint4*>(&Kg[base]);
            const uint4 k1 = *reinterpret_cast<const uint4*>(&Kg[base + 8]);
            const uint4 v0 = *reinterpret_cast<const uint4*>(&Vg[base]);
            const uint4 v1 = *reinterpret_cast<const uint4*>(&Vg[base + 8]);
            *reinterpret_cast<uint4*>(&Kl[ml * 8])           = k0;
            *reinterpret_cast<uint4*>(&Kl[ANH * 8 + ml * 8]) = k1;
            *reinterpret_cast<uint4*>(&Vl[ml * 8])           = v0;
            *reinterpret_cast<uint4*>(&Vl[ANH * 8 + ml * 8]) = v1;
        }
    }
    __syncthreads();

    __half2 qh[8];
    qh[0] = u2h(q01.x); qh[1] = u2h(q01.y); qh[2] = u2h(q01.z); qh[3] = u2h(q01.w);
    qh[4] = u2h(q23.x); qh[5] = u2h(q23.y); qh[6] = u2h(q23.z); qh[7] = u2h(q23.w);

    const int mlc = (lz + 1) * 100 + (ly + 1) * 10 + (lx + 1);
    const uint4* kb = reinterpret_cast<const uint4*>(Kl) + mlc;
    const uint4* vb = reinterpret_cast<const uint4*>(Vl) + mlc;

    float s = 0.0f;
    __half2 av[8];
    #pragma unroll
    for (int i = 0; i < 8; ++i) av[i] = __float2half2_rn(0.0f);

    #pragma unroll
    for (int dz = -1; dz <= 1; ++dz) {
        #pragma unroll
        for (int dy = -1; dy <= 1; ++dy) {
            #pragma unroll
            for (int dx = -1; dx <= 1; ++dx) {
                const int off = dz * 100 + dy * 10 + dx;
                const uint4 ka = kb[off];          // ch 0-7  (4x f16x2)
                const uint4 kc = kb[off + ANH];    // ch 8-15

                __half2 acc2 = __hmul2(qh[0], u2h(ka.x));
                acc2 = __hfma2(qh[1], u2h(ka.y), acc2);
                acc2 = __hfma2(qh[2], u2h(ka.z), acc2);
                acc2 = __hfma2(qh[3], u2h(ka.w), acc2);
                acc2 = __hfma2(qh[4], u2h(kc.x), acc2);
                acc2 = __hfma2(qh[5], u2h(kc.y), acc2);
                acc2 = __hfma2(qh[6], u2h(kc.z), acc2);
                acc2 = __hfma2(qh[7], u2h(kc.w), acc2);
                const float lg = __low2float(acc2) + __high2float(acc2);

                // max-free softmax: logits ~N(0,1); e^|lg| far from f32 limit
                const float e = __expf(lg);
                s += e;
                // accumulate with e/16: f16 headroom to logit ~13.9
                const __half2 e2 = __float2half2_rn(e * 0.0625f);

                const uint4 va = vb[off];
                const uint4 vc = vb[off + ANH];
                av[0] = __hfma2(e2, u2h(va.x), av[0]);
                av[1] = __hfma2(e2, u2h(va.y), av[1]);
                av[2] = __hfma2(e2, u2h(va.z), av[2]);
                av[3] = __hfma2(e2, u2h(va.w), av[3]);
                av[4] = __hfma2(e2, u2h(vc.x), av[4]);
                av[5] = __hfma2(e2, u2h(vc.y), av[5]);
                av[6] = __hfma2(e2, u2h(vc.z), av[6]);
                av[7] = __hfma2(e2, u2h(vc.w), av[7]);
            }
        }
    }

    const float rs = 16.0f / s;              // undo the 1/16 scaling
    const int cb = h * HD;
    #pragma unroll
    for (int i = 0; i < 8; ++i) {
        const size_t i0 = (size_t)(cb + 2 * i) * NVOX + n;
        const size_t i1 = (size_t)(cb + 2 * i + 1) * NVOX + n;
        out[i0] = x[i0] + __low2float(av[i]) * rs;    // coalesced across lanes
        out[i1] = x[i1] + __high2float(av[i]) * rs;
    }
}

extern "C" void kernel_launch(void* const* d_in, const int* in_sizes, int n_in,
                              void* d_out, int out_size, void* d_ws, size_t ws_size,
                              hipStream_t stream) {
    const float* x  = (const float*)d_in[0];
    // d_in[1] = cemb (unused by the reference)
    const float* Wq = (const float*)d_in[2];
    const float* bq = (const float*)d_in[3];
    const float* Wk = (const float*)d_in[4];
    const float* bk = (const float*)d_in[5];
    const float* Wv = (const float*)d_in[6];
    const float* bv = (const float*)d_in[7];
    float* out = (float*)d_out;

    unsigned short* Qg = (unsigned short*)d_ws;        // f16 [N][64]
    unsigned short* Kg = Qg + (size_t)NVOX * CCH;      // f16 [N][64]
    unsigned short* Vg = Kg + (size_t)NVOX * CCH;      // f16 [N][64]

    proj_mfma<<<dim3(1000), dim3(256), 0, stream>>>(
        x, Wq, bq, Wk, bk, Wv, bv, Qg, Kg, Vg);
    attn_kernel<<<dim3(1000), dim3(256), 0, stream>>>(
        x, Qg, Kg, Vg, out);
}

// Round 12
// 37.000 us; speedup vs baseline: 2.0242x; 1.0302x over previous
//
#include <hip/hip_runtime.h>
#include <hip/hip_fp16.h>

// Local attention block: 40^3 volume, C=64, 4 heads of hd=16, 3x3x3 window,
// replicate padding, residual add. f32 in/out.
//
// All intermediates FP16. Kernel 1: proj via MFMA 16x16x32 f16, W-pack
// folded in; Q,K,V -> f16 [N][64], Q pre-scaled 1/4 (round-11, unchanged).
// Kernel 2: attention, block = (4x8x8 tile, ONE head), 512 threads: thread
// PAIR shares a voxel (even lane: ch 0-7, odd: ch 8-15). Per neighbor:
// 16B K read + 4 hfma2 + DPP xor-1 pair-reduce + exp + 4 hfma2 PV.
// 8 waves/SIMD (31/CU avg) for latency hiding; e/16 PV scaling for f16
// headroom.

#define NVOX 64000   // 40*40*40
#define DIM 40
#define CCH 64
#define HEADS 4
#define HD 16

// attn tile geometry (one head per block)
#define ATZ 4
#define ATY 8
#define ATX 8
#define ANH 600           // 6*10*10 halo voxels

typedef __attribute__((ext_vector_type(8))) _Float16 f16x8;
typedef __attribute__((ext_vector_type(4))) float f32x4;

__device__ __forceinline__ unsigned pkh(float a, float b) {
    __half2 h = __floats2half2_rn(a, b);
    return *reinterpret_cast<unsigned*>(&h);
}
__device__ __forceinline__ __half2 u2h(unsigned u) {
    __half2 h; *reinterpret_cast<unsigned*>(&h) = u; return h;
}

__device__ __forceinline__ int xcd_swz(int b) {   // bijective, 1000 % 8 == 0
    return (b & 7) * 125 + (b >> 3);
}

__global__ __launch_bounds__(256) void proj_mfma(
    const float* __restrict__ x,
    const float* __restrict__ Wq, const float* __restrict__ bq,
    const float* __restrict__ Wk, const float* __restrict__ bk,
    const float* __restrict__ Wv, const float* __restrict__ bv,
    unsigned short* __restrict__ Qg, unsigned short* __restrict__ Kg,
    unsigned short* __restrict__ Vg)
{
    // All LDS tiles 16B-granular: [chunk][row/vox][8 ch] -> 16 B lane stride.
    __shared__ __align__(16) unsigned short Wl[8 * 192 * 8];  // 24576 B
    __shared__ __align__(16) unsigned short xl[8 * 64 * 8];   //  8192 B
    __shared__ __align__(16) float bl[192];                   //   768 B

    const int tid = threadIdx.x;
    const int bid = xcd_swz((int)blockIdx.x);
    const int n0 = bid * 64;

    // ---- Stage W + bias: thread t<192 owns one output row ----
    if (tid < 192) {
        const float* Wsrc; const float* bsrc; float sc; int r;
        if (tid < 64)       { Wsrc = Wq; bsrc = bq; sc = 0.25f; r = tid; }
        else if (tid < 128) { Wsrc = Wk; bsrc = bk; sc = 1.0f;  r = tid - 64; }
        else                { Wsrc = Wv; bsrc = bv; sc = 1.0f;  r = tid - 128; }
        const float4* wr = reinterpret_cast<const float4*>(Wsrc + r * 64);
        #pragma unroll
        for (int c = 0; c < 8; ++c) {            // chunk = 8 ch = 2 float4
            const float4 f0 = wr[2 * c], f1 = wr[2 * c + 1];
            *reinterpret_cast<uint4*>(&Wl[(c * 192 + tid) * 8]) =
                make_uint4(pkh(sc * f0.x, sc * f0.y), pkh(sc * f0.z, sc * f0.w),
                           pkh(sc * f1.x, sc * f1.y), pkh(sc * f1.z, sc * f1.w));
        }
        bl[tid] = sc * bsrc[r];
    }
    // ---- Stage x tile: 512 items = (chunk, vox) ----
    #pragma unroll
    for (int i = 0; i < 2; ++i) {
        const int item = tid + i * 256;
        const int v = item & 63, c = item >> 6;      // c: 0..3 then 4..7
        float f[8];
        #pragma unroll
        for (int j = 0; j < 8; ++j)
            f[j] = x[(c * 8 + j) * NVOX + n0 + v];   // coalesced across lanes
        *reinterpret_cast<uint4*>(&xl[(c * 64 + v) * 8]) =
            make_uint4(pkh(f[0], f[1]), pkh(f[2], f[3]),
                       pkh(f[4], f[5]), pkh(f[6], f[7]));
    }
    __syncthreads();

    const int lane = tid & 63;
    const int wv   = tid >> 6;
    const int l15  = lane & 15;
    const int l4   = lane >> 4;
    const int vox  = wv * 16 + l15;
    const int n    = n0 + vox;               // D col = lane&15 -> voxel

    const f16x8 bx0 = *reinterpret_cast<const f16x8*>(&xl[(l4 * 64 + vox) * 8]);
    const f16x8 bx1 = *reinterpret_cast<const f16x8*>(&xl[((l4 + 4) * 64 + vox) * 8]);

    #pragma unroll
    for (int rb = 0; rb < 12; ++rb) {
        const int row = rb * 16 + l15;       // A row, k-chunks l4 / l4+4
        const f16x8 a0 = *reinterpret_cast<const f16x8*>(&Wl[(l4 * 192 + row) * 8]);
        const f16x8 a1 = *reinterpret_cast<const f16x8*>(&Wl[((l4 + 4) * 192 + row) * 8]);

        f32x4 acc = {0.f, 0.f, 0.f, 0.f};
        acc = __builtin_amdgcn_mfma_f32_16x16x32_f16(a0, bx0, acc, 0, 0, 0);
        acc = __builtin_amdgcn_mfma_f32_16x16x32_f16(a1, bx1, acc, 0, 0, 0);

        const int r0 = rb * 16 + l4 * 4;     // D rows r0..r0+3 for this lane
        const float4 bs = *reinterpret_cast<const float4*>(&bl[r0]);
        const int rr = r0 & 63;              // row within its matrix
        unsigned short* og = (rb < 4) ? Qg : (rb < 8) ? Kg : Vg;
        *reinterpret_cast<uint2*>(&og[(size_t)n * CCH + rr]) =
            make_uint2(pkh(acc[0] + bs.x, acc[1] + bs.y),
                       pkh(acc[2] + bs.z, acc[3] + bs.w));
    }
}

__global__ __launch_bounds__(512, 8) void attn_kernel(
    const float* __restrict__ x,
    const unsigned short* __restrict__ Qg, const unsigned short* __restrict__ Kg,
    const unsigned short* __restrict__ Vg,
    float* __restrict__ out)
{
    // LDS per matrix: [half(8ch)][600 halo voxels][8 f16] -> 16 B lane stride
    __shared__ __align__(16) unsigned short Kl[2 * ANH * 8];   // 19200 B
    __shared__ __align__(16) unsigned short Vl[2 * ANH * 8];   // 19200 B

    const int tid = threadIdx.x;
    const int bid = xcd_swz((int)blockIdx.x);   // 250 tiles x 4 heads
    const int h    = bid & 3;
    const int tile = bid >> 2;
    const int tx = tile % 5;
    const int ty = (tile / 5) % 5;
    const int tz = tile / 25;
    const int z0 = tz * ATZ - 1, y0 = ty * ATY - 1, x0 = tx * ATX - 1;

    // ---- Thread pair shares a voxel; part selects the 8-channel half ----
    const int vox  = tid >> 1;             // 0..255
    const int part = tid & 1;              // 0: ch 0-7, 1: ch 8-15
    const int lz = vox >> 6, ly = (vox >> 3) & 7, lx = vox & 7;
    const int gz = tz * ATZ + lz, gy = ty * ATY + ly, gx = tx * ATX + lx;
    const int n = (gz * DIM + gy) * DIM + gx;

    // Q: this thread's 8 channels (16 B), issued before staging.
    const uint4 qw = *reinterpret_cast<const uint4*>(
        &Qg[(size_t)n * CCH + h * HD + part * 8]);

    // ---- Stage K+V halo: 600 items, 32 B of K + 32 B of V each ----
    #pragma unroll
    for (int i = 0; i < 2; ++i) {
        const int ml = tid + i * 512;
        if (ml < ANH) {
            const int hz = ml / 100; const int r = ml - hz * 100;
            const int hy = r / 10;   const int hx = r - hy * 10;
            const int sz = min(max(z0 + hz, 0), DIM - 1);
            const int sy = min(max(y0 + hy, 0), DIM - 1);
            const int sx = min(max(x0 + hx, 0), DIM - 1);
            const size_t base = (size_t)((sz * DIM + sy) * DIM + sx) * CCH + h * HD;
            const uint4 k0 = *reinterpret_cast<const uint4*>(&Kg[base]);
            const uint4 k1 = *reinterpret_cast<const uint4*>(&Kg[base + 8]);
            const uint4 v0 = *reinterpret_cast<const uint4*>(&Vg[base]);
            const uint4 v1 = *reinterpret_cast<const uint4*>(&Vg[base + 8]);
            *reinterpret_cast<uint4*>(&Kl[ml * 8])           = k0;
            *reinterpret_cast<uint4*>(&Kl[ANH * 8 + ml * 8]) = k1;
            *reinterpret_cast<uint4*>(&Vl[ml * 8])           = v0;
            *reinterpret_cast<uint4*>(&Vl[ANH * 8 + ml * 8]) = v1;
        }
    }
    __syncthreads();

    __half2 qh[4];
    qh[0] = u2h(qw.x); qh[1] = u2h(qw.y); qh[2] = u2h(qw.z); qh[3] = u2h(qw.w);

    const int mlc = (lz + 1) * 100 + (ly + 1) * 10 + (lx + 1);
    const uint4* kb = reinterpret_cast<const uint4*>(Kl) + part * ANH + mlc;
    const uint4* vb = reinterpret_cast<const uint4*>(Vl) + part * ANH + mlc;

    float s = 0.0f;
    __half2 av[4];
    #pragma unroll
    for (int i = 0; i < 4; ++i) av[i] = __float2half2_rn(0.0f);

    #pragma unroll
    for (int dz = -1; dz <= 1; ++dz) {
        #pragma unroll
        for (int dy = -1; dy <= 1; ++dy) {
            #pragma unroll
            for (int dx = -1; dx <= 1; ++dx) {
                const int off = dz * 100 + dy * 10 + dx;
                const uint4 k = kb[off];           // this part's 8 ch (4x f16x2)

                __half2 acc2 = __hmul2(qh[0], u2h(k.x));
                acc2 = __hfma2(qh[1], u2h(k.y), acc2);
                acc2 = __hfma2(qh[2], u2h(k.z), acc2);
                acc2 = __hfma2(qh[3], u2h(k.w), acc2);
                const float lgh = __low2float(acc2) + __high2float(acc2);
                // pair-reduce: DPP quad_perm [1,0,3,2] swaps lane^1 (pure VALU)
                const int oth = __builtin_amdgcn_mov_dpp(
                    __float_as_int(lgh), 0xB1, 0xF, 0xF, true);
                const float lg = lgh + __int_as_float(oth);

                // max-free softmax: logits ~N(0,1); e^|lg| far from f32 limit
                const float e = __expf(lg);
                s += e;
                // accumulate with e/16: f16 headroom to logit ~13.9
                const __half2 e2 = __float2half2_rn(e * 0.0625f);

                const uint4 v = vb[off];
                av[0] = __hfma2(e2, u2h(v.x), av[0]);
                av[1] = __hfma2(e2, u2h(v.y), av[1]);
                av[2] = __hfma2(e2, u2h(v.z), av[2]);
                av[3] = __hfma2(e2, u2h(v.w), av[3]);
            }
        }
    }

    const float rs = 16.0f / s;              // undo the 1/16 scaling
    const int cb = h * HD + part * 8;
    #pragma unroll
    for (int i = 0; i < 4; ++i) {
        const size_t i0 = (size_t)(cb + 2 * i) * NVOX + n;
        const size_t i1 = (size_t)(cb + 2 * i + 1) * NVOX + n;
        out[i0] = x[i0] + __low2float(av[i]) * rs;
        out[i1] = x[i1] + __high2float(av[i]) * rs;
    }
}

extern "C" void kernel_launch(void* const* d_in, const int* in_sizes, int n_in,
                              void* d_out, int out_size, void* d_ws, size_t ws_size,
                              hipStream_t stream) {
    const float* x  = (const float*)d_in[0];
    // d_in[1] = cemb (unused by the reference)
    const float* Wq = (const float*)d_in[2];
    const float* bq = (const float*)d_in[3];
    const float* Wk = (const float*)d_in[4];
    const float* bk = (const float*)d_in[5];
    const float* Wv = (const float*)d_in[6];
    const float* bv = (const float*)d_in[7];
    float* out = (float*)d_out;

    unsigned short* Qg = (unsigned short*)d_ws;        // f16 [N][64]
    unsigned short* Kg = Qg + (size_t)NVOX * CCH;      // f16 [N][64]
    unsigned short* Vg = Kg + (size_t)NVOX * CCH;      // f16 [N][64]

    proj_mfma<<<dim3(1000), dim3(256), 0, stream>>>(
        x, Wq, bq, Wk, bk, Wv, bv, Qg, Kg, Vg);
    attn_kernel<<<dim3(1000), dim3(512), 0, stream>>>(
        x, Qg, Kg, Vg, out);
}

// Round 13
// 35.023 us; speedup vs baseline: 2.1385x; 1.0564x over previous
//
#include <hip/hip_runtime.h>
#include <hip/hip_fp16.h>

// Local attention block: 40^3 volume, C=64, 4 heads of hd=16, 3x3x3 window,
// replicate padding, residual add. f32 in/out.
//
// All intermediates FP16.
// Kernel 1: proj via MFMA 16x16x32 f16. 500 blocks x 512 threads, 128
//           voxels/block: W-stage (f32->f16 LDS, Q rows pre-scaled 1/4)
//           amortized 2x vs round-12 and spread over all threads; x
//           B-fragments loaded DIRECT to registers (issued before the W
//           barrier -> latency hidden; no LDS round-trip).
// Kernel 2: attention (round-12, unchanged): block = (4x8x8 tile, ONE
//           head), 512 threads, thread-pair per voxel (8ch halves), DPP
//           xor-1 pair reduce, packed-f16 hfma2, e/16 PV scaling.

#define NVOX 64000   // 40*40*40
#define DIM 40
#define CCH 64
#define HEADS 4
#define HD 16

// attn tile geometry (one head per block)
#define ATZ 4
#define ATY 8
#define ATX 8
#define ANH 600           // 6*10*10 halo voxels

typedef __attribute__((ext_vector_type(8))) _Float16 f16x8;
typedef __attribute__((ext_vector_type(4))) float f32x4;

__device__ __forceinline__ unsigned pkh(float a, float b) {
    __half2 h = __floats2half2_rn(a, b);
    return *reinterpret_cast<unsigned*>(&h);
}
__device__ __forceinline__ __half2 u2h(unsigned u) {
    __half2 h; *reinterpret_cast<unsigned*>(&h) = u; return h;
}

__device__ __forceinline__ int xcd_swz(int b) {   // bijective, 1000 % 8 == 0
    return (b & 7) * 125 + (b >> 3);
}
__device__ __forceinline__ int xcd_swz500(int b) { // bijective for 500 (m204)
    const int xcd = b & 7, loc = b >> 3;           // q=62, r=4
    return (xcd < 4 ? xcd * 63 : 252 + (xcd - 4) * 62) + loc;
}

__global__ __launch_bounds__(512) void proj_mfma(
    const float* __restrict__ x,
    const float* __restrict__ Wq, const float* __restrict__ bq,
    const float* __restrict__ Wk, const float* __restrict__ bk,
    const float* __restrict__ Wv, const float* __restrict__ bv,
    unsigned short* __restrict__ Qg, unsigned short* __restrict__ Kg,
    unsigned short* __restrict__ Vg)
{
    // W LDS: [chunk(8ch)][192 rows][8 f16] -> 16 B lane stride (conflict-free)
    __shared__ __align__(16) unsigned short Wl[8 * 192 * 8];  // 24576 B
    __shared__ __align__(16) float bl[192];                   //   768 B

    const int tid = threadIdx.x;
    const int bid = xcd_swz500((int)blockIdx.x);
    const int n0 = bid * 128;                // 500 * 128 = 64000

    const int lane = tid & 63;
    const int wv   = tid >> 6;               // 8 waves -> 8 voxel-16-tiles
    const int l15  = lane & 15;
    const int l4   = lane >> 4;
    const int vox  = wv * 16 + l15;
    const int n    = n0 + vox;               // D col = lane&15 -> voxel

    // ---- x B-fragments direct to registers; issue BEFORE the W barrier ----
    float xf[16];
    #pragma unroll
    for (int j = 0; j < 8; ++j)
        xf[j] = x[(l4 * 8 + j) * NVOX + n];          // 64B-segment coalesced
    #pragma unroll
    for (int j = 0; j < 8; ++j)
        xf[8 + j] = x[(32 + l4 * 8 + j) * NVOX + n];

    // ---- Stage W + bias: 1536 items over 512 threads (3 each) ----
    #pragma unroll
    for (int i = 0; i < 3; ++i) {
        const int item = tid + i * 512;
        const int row = item % 192, chunk = item / 192;
        const float* Wsrc; float sc; int r;
        if (row < 64)       { Wsrc = Wq; sc = 0.25f; r = row; }
        else if (row < 128) { Wsrc = Wk; sc = 1.0f;  r = row - 64; }
        else                { Wsrc = Wv; sc = 1.0f;  r = row - 128; }
        const float4 f0 = *reinterpret_cast<const float4*>(&Wsrc[r * 64 + chunk * 8]);
        const float4 f1 = *reinterpret_cast<const float4*>(&Wsrc[r * 64 + chunk * 8 + 4]);
        *reinterpret_cast<uint4*>(&Wl[(chunk * 192 + row) * 8]) =
            make_uint4(pkh(sc * f0.x, sc * f0.y), pkh(sc * f0.z, sc * f0.w),
                       pkh(sc * f1.x, sc * f1.y), pkh(sc * f1.z, sc * f1.w));
    }
    if (tid < 192) {
        const float* bsrc; float sc; int r;
        if (tid < 64)       { bsrc = bq; sc = 0.25f; r = tid; }
        else if (tid < 128) { bsrc = bk; sc = 1.0f;  r = tid - 64; }
        else                { bsrc = bv; sc = 1.0f;  r = tid - 128; }
        bl[tid] = sc * bsrc[r];
    }

    // Pack x fragments while W loads are in flight.
    union { unsigned u[4]; f16x8 v; } U0, U1;
    #pragma unroll
    for (int p = 0; p < 4; ++p) {
        U0.u[p] = pkh(xf[2 * p], xf[2 * p + 1]);
        U1.u[p] = pkh(xf[8 + 2 * p], xf[9 + 2 * p]);
    }
    const f16x8 bx0 = U0.v, bx1 = U1.v;

    __syncthreads();

    #pragma unroll
    for (int rb = 0; rb < 12; ++rb) {
        const int row = rb * 16 + l15;       // A row, k-chunks l4 / l4+4
        const f16x8 a0 = *reinterpret_cast<const f16x8*>(&Wl[(l4 * 192 + row) * 8]);
        const f16x8 a1 = *reinterpret_cast<const f16x8*>(&Wl[((l4 + 4) * 192 + row) * 8]);

        f32x4 acc = {0.f, 0.f, 0.f, 0.f};
        acc = __builtin_amdgcn_mfma_f32_16x16x32_f16(a0, bx0, acc, 0, 0, 0);
        acc = __builtin_amdgcn_mfma_f32_16x16x32_f16(a1, bx1, acc, 0, 0, 0);

        const int r0 = rb * 16 + l4 * 4;     // D rows r0..r0+3 for this lane
        const float4 bs = *reinterpret_cast<const float4*>(&bl[r0]);
        const int rr = r0 & 63;              // row within its matrix
        unsigned short* og = (rb < 4) ? Qg : (rb < 8) ? Kg : Vg;
        *reinterpret_cast<uint2*>(&og[(size_t)n * CCH + rr]) =
            make_uint2(pkh(acc[0] + bs.x, acc[1] + bs.y),
                       pkh(acc[2] + bs.z, acc[3] + bs.w));
    }
}

__global__ __launch_bounds__(512, 8) void attn_kernel(
    const float* __restrict__ x,
    const unsigned short* __restrict__ Qg, const unsigned short* __restrict__ Kg,
    const unsigned short* __restrict__ Vg,
    float* __restrict__ out)
{
    // LDS per matrix: [half(8ch)][600 halo voxels][8 f16] -> 16 B lane stride
    __shared__ __align__(16) unsigned short Kl[2 * ANH * 8];   // 19200 B
    __shared__ __align__(16) unsigned short Vl[2 * ANH * 8];   // 19200 B

    const int tid = threadIdx.x;
    const int bid = xcd_swz((int)blockIdx.x);   // 250 tiles x 4 heads
    const int h    = bid & 3;
    const int tile = bid >> 2;
    const int tx = tile % 5;
    const int ty = (tile / 5) % 5;
    const int tz = tile / 25;
    const int z0 = tz * ATZ - 1, y0 = ty * ATY - 1, x0 = tx * ATX - 1;

    // ---- Thread pair shares a voxel; part selects the 8-channel half ----
    const int vox  = tid >> 1;             // 0..255
    const int part = tid & 1;              // 0: ch 0-7, 1: ch 8-15
    const int lz = vox >> 6, ly = (vox >> 3) & 7, lx = vox & 7;
    const int gz = tz * ATZ + lz, gy = ty * ATY + ly, gx = tx * ATX + lx;
    const int n = (gz * DIM + gy) * DIM + gx;

    // Q: this thread's 8 channels (16 B), issued before staging.
    const uint4 qw = *reinterpret_cast<const uint4*>(
        &Qg[(size_t)n * CCH + h * HD + part * 8]);

    // ---- Stage K+V halo: 600 items, 32 B of K + 32 B of V each ----
    #pragma unroll
    for (int i = 0; i < 2; ++i) {
        const int ml = tid + i * 512;
        if (ml < ANH) {
            const int hz = ml / 100; const int r = ml - hz * 100;
            const int hy = r / 10;   const int hx = r - hy * 10;
            const int sz = min(max(z0 + hz, 0), DIM - 1);
            const int sy = min(max(y0 + hy, 0), DIM - 1);
            const int sx = min(max(x0 + hx, 0), DIM - 1);
            const size_t base = (size_t)((sz * DIM + sy) * DIM + sx) * CCH + h * HD;
            const uint4 k0 = *reinterpret_cast<const uint4*>(&Kg[base]);
            const uint4 k1 = *reinterpret_cast<const uint4*>(&Kg[base + 8]);
            const uint4 v0 = *reinterpret_cast<const uint4*>(&Vg[base]);
            const uint4 v1 = *reinterpret_cast<const uint4*>(&Vg[base + 8]);
            *reinterpret_cast<uint4*>(&Kl[ml * 8])           = k0;
            *reinterpret_cast<uint4*>(&Kl[ANH * 8 + ml * 8]) = k1;
            *reinterpret_cast<uint4*>(&Vl[ml * 8])           = v0;
            *reinterpret_cast<uint4*>(&Vl[ANH * 8 + ml * 8]) = v1;
        }
    }
    __syncthreads();

    __half2 qh[4];
    qh[0] = u2h(qw.x); qh[1] = u2h(qw.y); qh[2] = u2h(qw.z); qh[3] = u2h(qw.w);

    const int mlc = (lz + 1) * 100 + (ly + 1) * 10 + (lx + 1);
    const uint4* kb = reinterpret_cast<const uint4*>(Kl) + part * ANH + mlc;
    const uint4* vb = reinterpret_cast<const uint4*>(Vl) + part * ANH + mlc;

    float s = 0.0f;
    __half2 av[4];
    #pragma unroll
    for (int i = 0; i < 4; ++i) av[i] = __float2half2_rn(0.0f);

    #pragma unroll
    for (int dz = -1; dz <= 1; ++dz) {
        #pragma unroll
        for (int dy = -1; dy <= 1; ++dy) {
            #pragma unroll
            for (int dx = -1; dx <= 1; ++dx) {
                const int off = dz * 100 + dy * 10 + dx;
                const uint4 k = kb[off];           // this part's 8 ch (4x f16x2)

                __half2 acc2 = __hmul2(qh[0], u2h(k.x));
                acc2 = __hfma2(qh[1], u2h(k.y), acc2);
                acc2 = __hfma2(qh[2], u2h(k.z), acc2);
                acc2 = __hfma2(qh[3], u2h(k.w), acc2);
                const float lgh = __low2float(acc2) + __high2float(acc2);
                // pair-reduce: DPP quad_perm [1,0,3,2] swaps lane^1 (pure VALU)
                const int oth = __builtin_amdgcn_mov_dpp(
                    __float_as_int(lgh), 0xB1, 0xF, 0xF, true);
                const float lg = lgh + __int_as_float(oth);

                // max-free softmax: logits ~N(0,1); e^|lg| far from f32 limit
                const float e = __expf(lg);
                s += e;
                // accumulate with e/16: f16 headroom to logit ~13.9
                const __half2 e2 = __float2half2_rn(e * 0.0625f);

                const uint4 v = vb[off];
                av[0] = __hfma2(e2, u2h(v.x), av[0]);
                av[1] = __hfma2(e2, u2h(v.y), av[1]);
                av[2] = __hfma2(e2, u2h(v.z), av[2]);
                av[3] = __hfma2(e2, u2h(v.w), av[3]);
            }
        }
    }

    const float rs = 16.0f / s;              // undo the 1/16 scaling
    const int cb = h * HD + part * 8;
    #pragma unroll
    for (int i = 0; i < 4; ++i) {
        const size_t i0 = (size_t)(cb + 2 * i) * NVOX + n;
        const size_t i1 = (size_t)(cb + 2 * i + 1) * NVOX + n;
        out[i0] = x[i0] + __low2float(av[i]) * rs;
        out[i1] = x[i1] + __high2float(av[i]) * rs;
    }
}

extern "C" void kernel_launch(void* const* d_in, const int* in_sizes, int n_in,
                              void* d_out, int out_size, void* d_ws, size_t ws_size,
                              hipStream_t stream) {
    const float* x  = (const float*)d_in[0];
    // d_in[1] = cemb (unused by the reference)
    const float* Wq = (const float*)d_in[2];
    const float* bq = (const float*)d_in[3];
    const float* Wk = (const float*)d_in[4];
    const float* bk = (const float*)d_in[5];
    const float* Wv = (const float*)d_in[6];
    const float* bv = (const float*)d_in[7];
    float* out = (float*)d_out;

    unsigned short* Qg = (unsigned short*)d_ws;        // f16 [N][64]
    unsigned short* Kg = Qg + (size_t)NVOX * CCH;      // f16 [N][64]
    unsigned short* Vg = Kg + (size_t)NVOX * CCH;      // f16 [N][64]

    proj_mfma<<<dim3(500), dim3(512), 0, stream>>>(
        x, Wq, bq, Wk, bk, Wv, bv, Qg, Kg, Vg);
    attn_kernel<<<dim3(1000), dim3(512), 0, stream>>>(
        x, Qg, Kg, Vg, out);
}

// Round 14
// 28.257 us; speedup vs baseline: 2.6506x; 1.2395x over previous
//
#include <hip/hip_runtime.h>
#include <hip/hip_fp16.h>

// Local attention block: 40^3 volume, C=64, 4 heads of hd=16, 3x3x3 window,
// replicate padding, residual add. f32 in/out.
//
// All intermediates FP16. QKV stored HEAD-PLANAR [head][N][16ch] so each
// attention block (one head) reads dense 32 B/voxel runs -> no cacheline
// over-fetch (round-10 profile: 94 MB FETCH vs 49 MB unique, from [N][64]
// layout splitting each voxel line across 4 head-blocks).
// Kernel 1: proj via MFMA 16x16x32 f16. 500 blocks x 512 threads; W-stage
//           f32->f16 LDS spread over all threads; x B-fragments direct to
//           registers (issued before the W barrier).
// Kernel 2: attention: block = (4x8x8 tile, ONE head), 512 threads,
//           thread-pair per voxel (8ch halves), DPP xor-1 pair reduce,
//           packed-f16 hfma2, e/16 PV scaling.

#define NVOX 64000   // 40*40*40
#define DIM 40
#define CCH 64
#define HEADS 4
#define HD 16
#define HPL (NVOX * HD)   // head-plane stride in f16 elements

// attn tile geometry (one head per block)
#define ATZ 4
#define ATY 8
#define ATX 8
#define ANH 600           // 6*10*10 halo voxels

typedef __attribute__((ext_vector_type(8))) _Float16 f16x8;
typedef __attribute__((ext_vector_type(4))) float f32x4;

__device__ __forceinline__ unsigned pkh(float a, float b) {
    __half2 h = __floats2half2_rn(a, b);
    return *reinterpret_cast<unsigned*>(&h);
}
__device__ __forceinline__ __half2 u2h(unsigned u) {
    __half2 h; *reinterpret_cast<unsigned*>(&h) = u; return h;
}

__device__ __forceinline__ int xcd_swz(int b) {   // bijective, 1000 % 8 == 0
    return (b & 7) * 125 + (b >> 3);
}
__device__ __forceinline__ int xcd_swz500(int b) { // bijective for 500 (m204)
    const int xcd = b & 7, loc = b >> 3;           // q=62, r=4
    return (xcd < 4 ? xcd * 63 : 252 + (xcd - 4) * 62) + loc;
}

__global__ __launch_bounds__(512) void proj_mfma(
    const float* __restrict__ x,
    const float* __restrict__ Wq, const float* __restrict__ bq,
    const float* __restrict__ Wk, const float* __restrict__ bk,
    const float* __restrict__ Wv, const float* __restrict__ bv,
    unsigned short* __restrict__ Qg, unsigned short* __restrict__ Kg,
    unsigned short* __restrict__ Vg)
{
    // W LDS: [chunk(8ch)][192 rows][8 f16] -> 16 B lane stride (conflict-free)
    __shared__ __align__(16) unsigned short Wl[8 * 192 * 8];  // 24576 B
    __shared__ __align__(16) float bl[192];                   //   768 B

    const int tid = threadIdx.x;
    const int bid = xcd_swz500((int)blockIdx.x);
    const int n0 = bid * 128;                // 500 * 128 = 64000

    const int lane = tid & 63;
    const int wv   = tid >> 6;               // 8 waves -> 8 voxel-16-tiles
    const int l15  = lane & 15;
    const int l4   = lane >> 4;
    const int vox  = wv * 16 + l15;
    const int n    = n0 + vox;               // D col = lane&15 -> voxel

    // ---- x B-fragments direct to registers; issue BEFORE the W barrier ----
    float xf[16];
    #pragma unroll
    for (int j = 0; j < 8; ++j)
        xf[j] = x[(l4 * 8 + j) * NVOX + n];          // 64B-segment coalesced
    #pragma unroll
    for (int j = 0; j < 8; ++j)
        xf[8 + j] = x[(32 + l4 * 8 + j) * NVOX + n];

    // ---- Stage W + bias: 1536 items over 512 threads (3 each) ----
    #pragma unroll
    for (int i = 0; i < 3; ++i) {
        const int item = tid + i * 512;
        const int row = item % 192, chunk = item / 192;
        const float* Wsrc; float sc; int r;
        if (row < 64)       { Wsrc = Wq; sc = 0.25f; r = row; }
        else if (row < 128) { Wsrc = Wk; sc = 1.0f;  r = row - 64; }
        else                { Wsrc = Wv; sc = 1.0f;  r = row - 128; }
        const float4 f0 = *reinterpret_cast<const float4*>(&Wsrc[r * 64 + chunk * 8]);
        const float4 f1 = *reinterpret_cast<const float4*>(&Wsrc[r * 64 + chunk * 8 + 4]);
        *reinterpret_cast<uint4*>(&Wl[(chunk * 192 + row) * 8]) =
            make_uint4(pkh(sc * f0.x, sc * f0.y), pkh(sc * f0.z, sc * f0.w),
                       pkh(sc * f1.x, sc * f1.y), pkh(sc * f1.z, sc * f1.w));
    }
    if (tid < 192) {
        const float* bsrc; float sc; int r;
        if (tid < 64)       { bsrc = bq; sc = 0.25f; r = tid; }
        else if (tid < 128) { bsrc = bk; sc = 1.0f;  r = tid - 64; }
        else                { bsrc = bv; sc = 1.0f;  r = tid - 128; }
        bl[tid] = sc * bsrc[r];
    }

    // Pack x fragments while W loads are in flight.
    union { unsigned u[4]; f16x8 v; } U0, U1;
    #pragma unroll
    for (int p = 0; p < 4; ++p) {
        U0.u[p] = pkh(xf[2 * p], xf[2 * p + 1]);
        U1.u[p] = pkh(xf[8 + 2 * p], xf[9 + 2 * p]);
    }
    const f16x8 bx0 = U0.v, bx1 = U1.v;

    __syncthreads();

    #pragma unroll
    for (int rb = 0; rb < 12; ++rb) {
        const int row = rb * 16 + l15;       // A row, k-chunks l4 / l4+4
        const f16x8 a0 = *reinterpret_cast<const f16x8*>(&Wl[(l4 * 192 + row) * 8]);
        const f16x8 a1 = *reinterpret_cast<const f16x8*>(&Wl[((l4 + 4) * 192 + row) * 8]);

        f32x4 acc = {0.f, 0.f, 0.f, 0.f};
        acc = __builtin_amdgcn_mfma_f32_16x16x32_f16(a0, bx0, acc, 0, 0, 0);
        acc = __builtin_amdgcn_mfma_f32_16x16x32_f16(a1, bx1, acc, 0, 0, 0);

        const int r0 = rb * 16 + l4 * 4;     // D rows r0..r0+3 for this lane
        const float4 bs = *reinterpret_cast<const float4*>(&bl[r0]);

        // Head-planar store: matrix = rb>>2, head = rb&3, ch = l4*4.
        unsigned short* og = (rb < 4) ? Qg : (rb < 8) ? Kg : Vg;
        const size_t dst = (size_t)(rb & 3) * HPL + (size_t)n * HD + l4 * 4;
        *reinterpret_cast<uint2*>(&og[dst]) =
            make_uint2(pkh(acc[0] + bs.x, acc[1] + bs.y),
                       pkh(acc[2] + bs.z, acc[3] + bs.w));
    }
}

__global__ __launch_bounds__(512, 8) void attn_kernel(
    const float* __restrict__ x,
    const unsigned short* __restrict__ Qg, const unsigned short* __restrict__ Kg,
    const unsigned short* __restrict__ Vg,
    float* __restrict__ out)
{
    // LDS per matrix: [half(8ch)][600 halo voxels][8 f16] -> 16 B lane stride
    __shared__ __align__(16) unsigned short Kl[2 * ANH * 8];   // 19200 B
    __shared__ __align__(16) unsigned short Vl[2 * ANH * 8];   // 19200 B

    const int tid = threadIdx.x;
    const int bid = xcd_swz((int)blockIdx.x);   // 250 tiles x 4 heads
    const int h    = bid & 3;
    const int tile = bid >> 2;
    const int tx = tile % 5;
    const int ty = (tile / 5) % 5;
    const int tz = tile / 25;
    const int z0 = tz * ATZ - 1, y0 = ty * ATY - 1, x0 = tx * ATX - 1;

    const unsigned short* Qh = Qg + (size_t)h * HPL;
    const unsigned short* Kh = Kg + (size_t)h * HPL;
    const unsigned short* Vh = Vg + (size_t)h * HPL;

    // ---- Thread pair shares a voxel; part selects the 8-channel half ----
    const int vox  = tid >> 1;             // 0..255
    const int part = tid & 1;              // 0: ch 0-7, 1: ch 8-15
    const int lz = vox >> 6, ly = (vox >> 3) & 7, lx = vox & 7;
    const int gz = tz * ATZ + lz, gy = ty * ATY + ly, gx = tx * ATX + lx;
    const int n = (gz * DIM + gy) * DIM + gx;

    // Q: this thread's 8 channels (16 B), issued before staging. Dense plane.
    const uint4 qw = *reinterpret_cast<const uint4*>(
        &Qh[(size_t)n * HD + part * 8]);

    // ---- Stage K+V halo: 600 items, 32 B of K + 32 B of V each (dense) ----
    #pragma unroll
    for (int i = 0; i < 2; ++i) {
        const int ml = tid + i * 512;
        if (ml < ANH) {
            const int hz = ml / 100; const int r = ml - hz * 100;
            const int hy = r / 10;   const int hx = r - hy * 10;
            const int sz = min(max(z0 + hz, 0), DIM - 1);
            const int sy = min(max(y0 + hy, 0), DIM - 1);
            const int sx = min(max(x0 + hx, 0), DIM - 1);
            const size_t base = (size_t)((sz * DIM + sy) * DIM + sx) * HD;
            const uint4 k0 = *reinterpret_cast<const uint4*>(&Kh[base]);
            const uint4 k1 = *reinterpret_cast<const uint4*>(&Kh[base + 8]);
            const uint4 v0 = *reinterpret_cast<const uint4*>(&Vh[base]);
            const uint4 v1 = *reinterpret_cast<const uint4*>(&Vh[base + 8]);
            *reinterpret_cast<uint4*>(&Kl[ml * 8])           = k0;
            *reinterpret_cast<uint4*>(&Kl[ANH * 8 + ml * 8]) = k1;
            *reinterpret_cast<uint4*>(&Vl[ml * 8])           = v0;
            *reinterpret_cast<uint4*>(&Vl[ANH * 8 + ml * 8]) = v1;
        }
    }
    __syncthreads();

    __half2 qh[4];
    qh[0] = u2h(qw.x); qh[1] = u2h(qw.y); qh[2] = u2h(qw.z); qh[3] = u2h(qw.w);

    const int mlc = (lz + 1) * 100 + (ly + 1) * 10 + (lx + 1);
    const uint4* kb = reinterpret_cast<const uint4*>(Kl) + part * ANH + mlc;
    const uint4* vb = reinterpret_cast<const uint4*>(Vl) + part * ANH + mlc;

    float s = 0.0f;
    __half2 av[4];
    #pragma unroll
    for (int i = 0; i < 4; ++i) av[i] = __float2half2_rn(0.0f);

    #pragma unroll
    for (int dz = -1; dz <= 1; ++dz) {
        #pragma unroll
        for (int dy = -1; dy <= 1; ++dy) {
            #pragma unroll
            for (int dx = -1; dx <= 1; ++dx) {
                const int off = dz * 100 + dy * 10 + dx;
                const uint4 k = kb[off];           // this part's 8 ch (4x f16x2)

                __half2 acc2 = __hmul2(qh[0], u2h(k.x));
                acc2 = __hfma2(qh[1], u2h(k.y), acc2);
                acc2 = __hfma2(qh[2], u2h(k.z), acc2);
                acc2 = __hfma2(qh[3], u2h(k.w), acc2);
                const float lgh = __low2float(acc2) + __high2float(acc2);
                // pair-reduce: DPP quad_perm [1,0,3,2] swaps lane^1 (pure VALU)
                const int oth = __builtin_amdgcn_mov_dpp(
                    __float_as_int(lgh), 0xB1, 0xF, 0xF, true);
                const float lg = lgh + __int_as_float(oth);

                // max-free softmax: logits ~N(0,1); e^|lg| far from f32 limit
                const float e = __expf(lg);
                s += e;
                // accumulate with e/16: f16 headroom to logit ~13.9
                const __half2 e2 = __float2half2_rn(e * 0.0625f);

                const uint4 v = vb[off];
                av[0] = __hfma2(e2, u2h(v.x), av[0]);
                av[1] = __hfma2(e2, u2h(v.y), av[1]);
                av[2] = __hfma2(e2, u2h(v.z), av[2]);
                av[3] = __hfma2(e2, u2h(v.w), av[3]);
            }
        }
    }

    const float rs = 16.0f / s;              // undo the 1/16 scaling
    const int cb = h * HD + part * 8;
    #pragma unroll
    for (int i = 0; i < 4; ++i) {
        const size_t i0 = (size_t)(cb + 2 * i) * NVOX + n;
        const size_t i1 = (size_t)(cb + 2 * i + 1) * NVOX + n;
        out[i0] = x[i0] + __low2float(av[i]) * rs;
        out[i1] = x[i1] + __high2float(av[i]) * rs;
    }
}

extern "C" void kernel_launch(void* const* d_in, const int* in_sizes, int n_in,
                              void* d_out, int out_size, void* d_ws, size_t ws_size,
                              hipStream_t stream) {
    const float* x  = (const float*)d_in[0];
    // d_in[1] = cemb (unused by the reference)
    const float* Wq = (const float*)d_in[2];
    const float* bq = (const float*)d_in[3];
    const float* Wk = (const float*)d_in[4];
    const float* bk = (const float*)d_in[5];
    const float* Wv = (const float*)d_in[6];
    const float* bv = (const float*)d_in[7];
    float* out = (float*)d_out;

    unsigned short* Qg = (unsigned short*)d_ws;        // f16 [4][N][16]
    unsigned short* Kg = Qg + (size_t)NVOX * CCH;      // f16 [4][N][16]
    unsigned short* Vg = Kg + (size_t)NVOX * CCH;      // f16 [4][N][16]

    proj_mfma<<<dim3(500), dim3(512), 0, stream>>>(
        x, Wq, bq, Wk, bk, Wv, bv, Qg, Kg, Vg);
    attn_kernel<<<dim3(1000), dim3(512), 0, stream>>>(
        x, Qg, Kg, Vg, out);
}